// Round 2
// baseline (328.447 us; speedup 1.0000x reference)
//
#include <hip/hip_runtime.h>
#include <hip/hip_bf16.h>
#include <math.h>

// Problem constants
#define B_   4
#define CIN  256
#define COUT 256
#define HW   4096   // 64*64

typedef __attribute__((ext_vector_type(8))) short short8;
typedef __attribute__((ext_vector_type(4))) float float4v;

// LDS row stride (ushorts). 80 B: 16B-aligned, period-8 bank pattern -> 2-way (free).
#define LSTR 40

__device__ __forceinline__ float sigmoidf_(float v){ return 1.0f/(1.0f+expf(-v)); }
__device__ __forceinline__ ushort f2bf(float f){
  union { float f; unsigned u; } x; x.f = f;
  unsigned r = x.u + 0x7fffu + ((x.u>>16)&1u);
  return (ushort)(r>>16);
}
__device__ __forceinline__ float bflo(unsigned u){ union{unsigned u; float f;} c; c.u = u<<16;          return c.f; }
__device__ __forceinline__ float bfhi(unsigned u){ union{unsigned u; float f;} c; c.u = u & 0xffff0000u; return c.f; }

// Raw barrier draining ONLY lgkmcnt (LDS visibility). Unlike __syncthreads(),
// this does NOT force vmcnt(0): global loads issued this phase stay in flight
// across the barrier; the compiler inserts exact counted vmcnt(N) at their use
// one phase later (T4). "memory" clobber pins LDS r/w ordering around it.
__device__ __forceinline__ void bar_lgkm(){
  asm volatile("s_waitcnt lgkmcnt(0)\n\ts_barrier" ::: "memory");
}

// ---------- transpose x [B][C][HW] -> xtb [B][HW][C] bf16 ----------
__global__ void k_transpose_x(const float* __restrict__ x, ushort* __restrict__ xtb){
  __shared__ float ts[32][33];
  int tx = threadIdx.x & 31, ty = threadIdx.x >> 5;
  int p0 = blockIdx.x * 32, c0 = blockIdx.y * 32, b = blockIdx.z;
  const float* xb = x + (size_t)b*CIN*HW;
#pragma unroll
  for(int q=0;q<4;q++){
    int c = ty + q*8;
    ts[c][tx] = xb[(size_t)(c0+c)*HW + p0+tx];
  }
  __syncthreads();
#pragma unroll
  for(int q=0;q<4;q++){
    int pr = ty + q*8;
    xtb[((size_t)(b*HW + p0+pr)<<8) + c0+tx] = f2bf(ts[tx][pr]);
  }
}

// ---------- weight re-layouts (bf16, K-chunked [kc][o][kk]) ----------
__global__ void k_build_Wob(const float* __restrict__ w_off, ushort* __restrict__ Wob){
  int f = blockIdx.x*256 + threadIdx.x;   // grid 288
  int kc = f>>10, o = (f>>5)&31, kk = f&31;
  int k = kc*32 + kk, tap = k>>8, c = k&255;
  float v = (o < 27) ? w_off[(size_t)o*2304 + c*9 + tap] : 0.f;
  Wob[f] = f2bf(v);
}
__global__ void k_build_Wdb(const float* __restrict__ w_dcn, ushort* __restrict__ Wdb){
  int f = blockIdx.x*256 + threadIdx.x;  // grid 2304
  int kc = f>>13, o = (f>>5)&255, kk = f&31;
  int k = kc>>3, c = ((kc&7)<<5) | kk;
  Wdb[f] = f2bf(w_dcn[(size_t)o*2304 + c*9 + k]);
}
__global__ void k_build_WT2c(const float* __restrict__ w_up, ushort* __restrict__ WT2c){
  int f = blockIdx.x*256 + threadIdx.x;    // grid 4096
  int pp = f>>18, kc = (f>>13)&31, o = (f>>5)&255, kk = f&31;
  int k = kc*32 + kk, ab = k>>8, c = k&255;
  int a = ab>>1, bb = ab&1, ph = pp>>1, pw = pp&1;
  WT2c[f] = f2bf(w_up[(size_t)(c*COUT+o)*16 + (3-ph-2*a)*4 + (3-pw-2*bb)]);
}

// ---------- offset conv MFMA: M=32(27), Nb=64 px, K=2304 ----------
// grid (64,4) = 256 blocks, 256 thr = 4 waves; wave wv owns px quarter, 2 m-tiles.
// W direct global->reg; V gathers 2-deep; Vs double-buffered; raw lgkm-only
// barriers keep prefetch loads in flight across phases (counted vmcnt).
__global__ __launch_bounds__(256) void k_offset_mfma(const ushort* __restrict__ xtb,
                        const ushort* __restrict__ Wob, float* __restrict__ om){
  __shared__ ushort Vs[2][64*LSTR];
  __shared__ int sIdx[576];
  int tid = threadIdx.x;
  int px0 = blockIdx.x * 64;
  int b   = blockIdx.y;
  for(int t=tid; t<576; t+=256){
    int tap = t>>6, px = t&63;
    int p = px0+px, hh = p>>6, ww = p&63;
    int ih = hh + tap/3 - 1, iw = ww + tap%3 - 1;
    sIdx[t] = (ih>=0 && ih<64 && iw>=0 && iw<64) ? ((b*HW + ih*64+iw)<<8) : -1;
  }
  bar_lgkm();

  int lane = tid&63, wv = tid>>6, lo = lane&15, hi = lane>>4;
  float4v acc[2];
  acc[0] = acc[1] = (float4v){0.f,0.f,0.f,0.f};
  int vpx = tid>>2, vseg = tid&3;
  const int wlane = lo*32 + hi*8;   // A-frag lane offset within a chunk

  short8 wA0, wA1, wB0, wB1;
  uint4 vE, vO;
  // ---- prologue: W chunk0 -> regs, V chunk0 -> Vs[0], V chunk1 -> regs ----
  wA0 = *(const short8*)(Wob + wlane);
  wA1 = *(const short8*)(Wob + wlane + 512);
  { int idx = sIdx[vpx];
    vE = make_uint4(0,0,0,0);
    if(idx >= 0) vE = *(const uint4*)(xtb + idx + (vseg<<3)); }
  *(uint4*)(&Vs[0][vpx*LSTR + (vseg<<3)]) = vE;
  { // kn=1: tap=0, c0=32
    int idx = sIdx[vpx];
    vO = make_uint4(0,0,0,0);
    if(idx >= 0) vO = *(const uint4*)(xtb + idx + 32 + (vseg<<3)); }
  bar_lgkm();

#pragma unroll 1
  for(int kcb=0; kcb<72; kcb+=2){
    { // even kc = kcb: compute chunk kcb (Vs[0], wA); gather kcb+2->vE; W kcb+1->wB; write vO->Vs[1]
      if(kcb<70){ int kn=kcb+2; int tap=kn>>3, c0=(kn&7)<<5;
        int idx = sIdx[(tap<<6)+vpx];
        vE = make_uint4(0,0,0,0);
        if(idx >= 0) vE = *(const uint4*)(xtb + idx + c0 + (vseg<<3)); }
      { const ushort* wp = Wob + ((kcb+1)<<10) + wlane;
        wB0 = *(const short8*)(wp); wB1 = *(const short8*)(wp + 512); }
      short8 bfr = *(const short8*)(&Vs[0][(wv*16+lo)*LSTR + hi*8]);
      acc[0] = __builtin_amdgcn_mfma_f32_16x16x32_bf16(wA0, bfr, acc[0], 0,0,0);
      acc[1] = __builtin_amdgcn_mfma_f32_16x16x32_bf16(wA1, bfr, acc[1], 0,0,0);
      *(uint4*)(&Vs[1][vpx*LSTR + (vseg<<3)]) = vO;
      bar_lgkm();
    }
    { // odd kc = kcb+1: compute chunk kcb+1 (Vs[1], wB); gather kcb+3->vO; W kcb+2->wA; write vE->Vs[0]
      if(kcb<69){ int kn=kcb+3; int tap=kn>>3, c0=(kn&7)<<5;
        int idx = sIdx[(tap<<6)+vpx];
        vO = make_uint4(0,0,0,0);
        if(idx >= 0) vO = *(const uint4*)(xtb + idx + c0 + (vseg<<3)); }
      if(kcb<70){ const ushort* wp = Wob + ((kcb+2)<<10) + wlane;
        wA0 = *(const short8*)(wp); wA1 = *(const short8*)(wp + 512); }
      short8 bfr = *(const short8*)(&Vs[1][(wv*16+lo)*LSTR + hi*8]);
      acc[0] = __builtin_amdgcn_mfma_f32_16x16x32_bf16(wB0, bfr, acc[0], 0,0,0);
      acc[1] = __builtin_amdgcn_mfma_f32_16x16x32_bf16(wB1, bfr, acc[1], 0,0,0);
      if(kcb<70) *(uint4*)(&Vs[0][vpx*LSTR + (vseg<<3)]) = vE;
      bar_lgkm();
    }
  }
  int p = px0 + wv*16 + lo;
#pragma unroll
  for(int mi=0;mi<2;mi++){
    int ob = mi*16 + hi*4;
    float4v a = (mi==0) ? acc[0] : acc[1];
#pragma unroll
    for(int r=0;r<4;r++){
      int o = ob + r;
      if(o < 27) om[(size_t)(b*27+o)*HW + p] = a[r];
    }
  }
}

// ---------- DCN MFMA: Mb=256, Nb=64, K=2304 ----------
// grid (64,4) = 256 blocks, 512 thr = 8 waves (2/SIMD).
// Wave wv: o-strip (wv>>1)*64, px-half (wv&1)*32 -> 4x2 tiles = 8 MFMA/iter.
// W direct global->reg, 1-chunk prefetch; gathers 2-deep (even/odd reg stages);
// Vs double-buffered; raw lgkm-only barriers (loads live across phases, T4).
// b_dcn dropped: BN1 subtracts the per-channel mean, so a uniform bias cancels.
#define DCN_GATHER(KN, CP0,CP1,CP2,CP3, CF) do{ \
    int k_ = (KN)>>3, c0_ = ((KN)&7)<<5; \
    int t_ = (k_<<6) + vpx; \
    int pk_ = sPk[t_]; CF = sCf[t_]; \
    int coff_ = c0_ + (vseg<<2); \
    int iy0_=pk_&63, iy1_=(pk_>>6)&63, ix0_=(pk_>>12)&63, ix1_=(pk_>>18)&63; \
    CP0 = *(const uint2*)(xtb + cbase + (((iy0_<<6)+ix0_)<<8) + coff_); \
    CP1 = *(const uint2*)(xtb + cbase + (((iy0_<<6)+ix1_)<<8) + coff_); \
    CP2 = *(const uint2*)(xtb + cbase + (((iy1_<<6)+ix0_)<<8) + coff_); \
    CP3 = *(const uint2*)(xtb + cbase + (((iy1_<<6)+ix1_)<<8) + coff_); \
  }while(0)

#define DCN_BLEND(CP0,CP1,CP2,CP3, CF, BUF) do{ \
    union{ ushort us[4]; uint2 q; } rr_; \
    rr_.us[0] = f2bf(CF.x*bflo(CP0.x)+CF.y*bflo(CP1.x)+CF.z*bflo(CP2.x)+CF.w*bflo(CP3.x)); \
    rr_.us[1] = f2bf(CF.x*bfhi(CP0.x)+CF.y*bfhi(CP1.x)+CF.z*bfhi(CP2.x)+CF.w*bfhi(CP3.x)); \
    rr_.us[2] = f2bf(CF.x*bflo(CP0.y)+CF.y*bflo(CP1.y)+CF.z*bflo(CP2.y)+CF.w*bflo(CP3.y)); \
    rr_.us[3] = f2bf(CF.x*bfhi(CP0.y)+CF.y*bfhi(CP1.y)+CF.z*bfhi(CP2.y)+CF.w*bfhi(CP3.y)); \
    *(uint2*)(&Vs[BUF][vpx*LSTR + (vseg<<2)]) = rr_.q; \
  }while(0)

__global__ __launch_bounds__(512) void k_dcn_mfma(const ushort* __restrict__ xtb,
                        const float* __restrict__ om, const float* __restrict__ b_off,
                        const ushort* __restrict__ Wdb, float* __restrict__ out1){
  __shared__ ushort Vs[2][64*LSTR];    // 2 x 5120 B
  __shared__ int    sPk[576];
  __shared__ float4 sCf[576];
  int tid = threadIdx.x;
  int px0 = blockIdx.x * 64;
  int b   = blockIdx.y;

  for(int t=tid; t<576; t+=512){
    int k = t>>6, px = t&63;
    int p = px0 + px, hh = p>>6, ww = p&63;
    const float* omp = om + (size_t)b*27*HW + p;
    float dy = omp[(size_t)k*HW]      + b_off[k];
    float dx = omp[(size_t)(9+k)*HW]  + b_off[9+k];
    float mo = sigmoidf_(omp[(size_t)(18+k)*HW] + b_off[18+k]);
    float py  = dy + (float)(hh + k/3 - 1);
    float pxf = dx + (float)(ww + k%3 - 1);
    float y0 = floorf(py), x0 = floorf(pxf);
    float wy = py - y0, wx = pxf - x0;
    float y1 = y0 + 1.0f, x1 = x0 + 1.0f;
    bool vy0 = (y0>=0.f)&&(y0<=63.f), vy1 = (y1>=0.f)&&(y1<=63.f);
    bool vx0 = (x0>=0.f)&&(x0<=63.f), vx1 = (x1>=0.f)&&(x1<=63.f);
    int iy0 = (int)fminf(fmaxf(y0,0.f),63.f);
    int iy1 = (int)fminf(fmaxf(y1,0.f),63.f);
    int ix0 = (int)fminf(fmaxf(x0,0.f),63.f);
    int ix1 = (int)fminf(fmaxf(x1,0.f),63.f);
    sPk[t] = iy0 | (iy1<<6) | (ix0<<12) | (ix1<<18);
    sCf[t] = make_float4((vy0&&vx0)? (1.f-wy)*(1.f-wx)*mo : 0.f,
                         (vy0&&vx1)? (1.f-wy)*wx*mo       : 0.f,
                         (vy1&&vx0)? wy*(1.f-wx)*mo       : 0.f,
                         (vy1&&vx1)? wy*wx*mo             : 0.f);
  }
  bar_lgkm();

  int lane = tid&63, wv = tid>>6, lo = lane&15, hi = lane>>4;
  int om0 = (wv>>1)*64, pn0 = (wv&1)*32;
  float4v acc[4][2];
#pragma unroll
  for(int i=0;i<4;i++)
#pragma unroll
    for(int j=0;j<2;j++) acc[i][j] = (float4v){0.f,0.f,0.f,0.f};
  int cbase = (b*HW)<<8;
  int vpx = tid>>3, vseg = tid&7;
  const int wlane = (om0+lo)*32 + hi*8;   // A-frag lane offset within a chunk

  short8 wA[4], wB[4];
  uint2 cE0,cE1,cE2,cE3, cO0,cO1,cO2,cO3;
  float4 fE, fO;

  // ---- prologue: W chunk0 -> wA, gather+blend chunk0 -> Vs[0], gather chunk1 -> O-stage ----
#pragma unroll
  for(int i=0;i<4;i++) wA[i] = *(const short8*)(Wdb + wlane + i*512);
  DCN_GATHER(0, cE0,cE1,cE2,cE3, fE);
  DCN_BLEND(cE0,cE1,cE2,cE3, fE, 0);
  DCN_GATHER(1, cO0,cO1,cO2,cO3, fO);
  bar_lgkm();

#pragma unroll 1
  for(int kcb=0; kcb<72; kcb+=2){
    { // even kc = kcb: compute chunk kcb (Vs[0], wA); gather kcb+2->E; W kcb+1->wB; blend O -> Vs[1]
      if(kcb<70) DCN_GATHER(kcb+2, cE0,cE1,cE2,cE3, fE);
      { const ushort* wp = Wdb + (((size_t)(kcb+1))<<13) + wlane;
#pragma unroll
        for(int i=0;i<4;i++) wB[i] = *(const short8*)(wp + i*512);
      }
      const ushort* bp = &Vs[0][(pn0 + lo)*LSTR + hi*8];
      short8 bfr0 = *(const short8*)(bp);
      short8 bfr1 = *(const short8*)(bp + 16*LSTR);
#pragma unroll
      for(int i=0;i<4;i++){
        acc[i][0] = __builtin_amdgcn_mfma_f32_16x16x32_bf16(wA[i], bfr0, acc[i][0], 0,0,0);
        acc[i][1] = __builtin_amdgcn_mfma_f32_16x16x32_bf16(wA[i], bfr1, acc[i][1], 0,0,0);
      }
      DCN_BLEND(cO0,cO1,cO2,cO3, fO, 1);
      bar_lgkm();
    }
    { // odd kc = kcb+1: compute chunk kcb+1 (Vs[1], wB); gather kcb+3->O; W kcb+2->wA; blend E -> Vs[0]
      if(kcb<69) DCN_GATHER(kcb+3, cO0,cO1,cO2,cO3, fO);
      if(kcb<70){
        const ushort* wp = Wdb + (((size_t)(kcb+2))<<13) + wlane;
#pragma unroll
        for(int i=0;i<4;i++) wA[i] = *(const short8*)(wp + i*512);
      }
      const ushort* bp = &Vs[1][(pn0 + lo)*LSTR + hi*8];
      short8 bfr0 = *(const short8*)(bp);
      short8 bfr1 = *(const short8*)(bp + 16*LSTR);
#pragma unroll
      for(int i=0;i<4;i++){
        acc[i][0] = __builtin_amdgcn_mfma_f32_16x16x32_bf16(wB[i], bfr0, acc[i][0], 0,0,0);
        acc[i][1] = __builtin_amdgcn_mfma_f32_16x16x32_bf16(wB[i], bfr1, acc[i][1], 0,0,0);
      }
      if(kcb<70) DCN_BLEND(cE0,cE1,cE2,cE3, fE, 0);
      bar_lgkm();
    }
  }

#pragma unroll
  for(int i=0;i<4;i++){
    int ob = om0 + i*16 + hi*4;
#pragma unroll
    for(int r=0;r<4;r++){
      int o = ob + r;
      float* op = out1 + (size_t)(b*COUT + o)*HW + px0 + pn0 + lo;
#pragma unroll
      for(int j=0;j<2;j++) op[j*16] = acc[i][j][r];
    }
  }
}

// ---------- batchnorm stats (f32 input, for out1) ----------
__global__ void k_bn_stats(const float* __restrict__ xin, float* __restrict__ stats, int per_b){
  int o = blockIdx.x, tid = threadIdx.x;
  float s=0.f, ss=0.f;
  for(int b=0;b<B_;b++){
    const float* p = xin + (size_t)(b*COUT+o)*per_b;
    for(int i=tid;i<per_b;i+=256){ float v = p[i]; s+=v; ss+=v*v; }
  }
  __shared__ float rs[256], rss[256];
  rs[tid]=s; rss[tid]=ss; __syncthreads();
  for(int st=128; st>0; st>>=1){
    if(tid<st){ rs[tid]+=rs[tid+st]; rss[tid]+=rss[tid+st]; }
    __syncthreads();
  }
  if(tid==0){
    float n = (float)(B_*per_b);
    float mean = rs[0]/n;
    float var  = rss[0]/n - mean*mean;
    stats[o*2] = mean; stats[o*2+1] = rsqrtf(var + 1e-5f);
  }
}

// ---------- batchnorm stats over bf16 ct [16 planes][o][4096] ----------
__global__ void k_bn_stats_ct(const ushort* __restrict__ ct, float* __restrict__ stats){
  int o = blockIdx.x, tid = threadIdx.x;
  float s=0.f, ss=0.f;
  for(int pl=0; pl<16; ++pl){
    const ushort* p = ct + (((size_t)(pl*256 + o))<<12);
    for(int i=tid*8; i<4096; i+=2048){
      uint4 v = *(const uint4*)(p + i);
      float f;
      f=bflo(v.x); s+=f; ss+=f*f;  f=bfhi(v.x); s+=f; ss+=f*f;
      f=bflo(v.y); s+=f; ss+=f*f;  f=bfhi(v.y); s+=f; ss+=f*f;
      f=bflo(v.z); s+=f; ss+=f*f;  f=bfhi(v.z); s+=f; ss+=f*f;
      f=bflo(v.w); s+=f; ss+=f*f;  f=bfhi(v.w); s+=f; ss+=f*f;
    }
  }
  __shared__ float rs[256], rss[256];
  rs[tid]=s; rss[tid]=ss; __syncthreads();
  for(int st=128; st>0; st>>=1){
    if(tid<st){ rs[tid]+=rs[tid+st]; rss[tid]+=rss[tid+st]; }
    __syncthreads();
  }
  if(tid==0){
    float n = (float)(16*4096);
    float mean = rs[0]/n;
    float var  = rss[0]/n - mean*mean;
    stats[o*2] = mean; stats[o*2+1] = rsqrtf(var + 1e-5f);
  }
}

// ---------- BN1 apply + relu + transpose -> y1b bf16 [b][p][c] ----------
__global__ void k_bn1_apply_t(const float* __restrict__ out1, const float* __restrict__ stats,
                              const float* __restrict__ gamma, const float* __restrict__ beta,
                              ushort* __restrict__ y1b){
  __shared__ float ts[32][33];
  int tx = threadIdx.x & 31, ty = threadIdx.x >> 5;
  int p0 = blockIdx.x*32, o0 = blockIdx.y*32, b = blockIdx.z;
#pragma unroll
  for(int q=0;q<4;q++){
    int oo = ty + q*8; int o = o0 + oo;
    float m = stats[o*2], rstd = stats[o*2+1];
    float scale = rstd * gamma[o];
    float shift = beta[o] - m * scale;
    float v = out1[(size_t)(b*COUT+o)*HW + p0+tx];
    ts[oo][tx] = fmaxf(v*scale + shift, 0.f);
  }
  __syncthreads();
#pragma unroll
  for(int q=0;q<4;q++){
    int pr = ty + q*8;
    y1b[((size_t)(b*HW + p0+pr)<<8) + o0+tx] = f2bf(ts[tx][pr]);
  }
}

// ---------- conv-transpose MFMA: Mb=256 o, Nb=256 px, one (b,pp); reg-prefetch ----------
// Raw lgkm-only barriers: W/V prefetch loads issued mid-iter stay in flight
// across the bottom barrier and are counted-waited at next iter's LDS write.
__global__ __launch_bounds__(512) void k_convt_mfma(const ushort* __restrict__ y1b,
                        const ushort* __restrict__ WT2c,
                        ushort* __restrict__ ct){
  __shared__ ushort Ws[256*LSTR];
  __shared__ ushort Vs[256*LSTR];
  __shared__ int sIdx[1024];
  int tid = threadIdx.x;
  int px0 = blockIdx.x * 256;
  int b   = blockIdx.y;
  int pp  = blockIdx.z;
  int ph = pp>>1, pw = pp&1;

  for(int t=tid; t<1024; t+=512){
    int ab = t>>8, px = t&255;
    int a = ab>>1, bb = ab&1;
    int p = px0+px, r = p>>6, s = p&63;
    int ih = r + ph - 1 + a, iw = s + pw - 1 + bb;
    sIdx[t] = (ih>=0 && ih<64 && iw>=0 && iw<64) ? ((b*HW + ih*64+iw)<<8) : -1;
  }
  bar_lgkm();

  int lane = tid&63, wv = tid>>6, lo = lane&15, hi = lane>>4;
  int om0 = (wv>>1)*64;
  int pn0 = (wv&1)*128;
  float4v acc[4][8];
#pragma unroll
  for(int i=0;i<4;i++)
#pragma unroll
    for(int j=0;j<8;j++) acc[i][j] = (float4v){0.f,0.f,0.f,0.f};

  const ushort* wbase = WT2c + ((size_t)pp<<18);
  uint4 wpre[2], vpre[2];
  { // prefetch kc=0
    wpre[0] = *(const uint4*)(wbase + tid*8);
    wpre[1] = *(const uint4*)(wbase + (tid+512)*8);
    int idx = sIdx[tid>>1];
    int co = (tid&1)*16;
    vpre[0] = vpre[1] = make_uint4(0,0,0,0);
    if(idx >= 0){
      vpre[0] = *(const uint4*)(y1b + idx + co);
      vpre[1] = *(const uint4*)(y1b + idx + co + 8);
    }
  }
#pragma unroll 1
  for(int kc=0; kc<32; ++kc){
    {
      int g1 = tid + 512;
      *(uint4*)(&Ws[(tid>>2)*LSTR + (tid&3)*8]) = wpre[0];
      *(uint4*)(&Ws[(g1>>2)*LSTR + (g1&3)*8])   = wpre[1];
      int vpx = tid>>1, co = (tid&1)*16;
      *(uint4*)(&Vs[vpx*LSTR + co])     = vpre[0];
      *(uint4*)(&Vs[vpx*LSTR + co + 8]) = vpre[1];
    }
    bar_lgkm();
    int kn = kc<31 ? kc+1 : kc;
    {
      const ushort* wp = wbase + (kn<<13);
      wpre[0] = *(const uint4*)(wp + tid*8);
      wpre[1] = *(const uint4*)(wp + (tid+512)*8);
      int ab = kn>>3, c0 = (kn&7)<<5;
      int idx = sIdx[(ab<<8) + (tid>>1)];
      int co = c0 + (tid&1)*16;
      vpre[0] = vpre[1] = make_uint4(0,0,0,0);
      if(idx >= 0){
        vpre[0] = *(const uint4*)(y1b + idx + co);
        vpre[1] = *(const uint4*)(y1b + idx + co + 8);
      }
    }
    const ushort* ap = &Ws[(om0 + lo)*LSTR + hi*8];
    const ushort* bp = &Vs[(pn0 + lo)*LSTR + hi*8];
    short8 bfr[8];
#pragma unroll
    for(int j=0;j<8;j++) bfr[j] = *(const short8*)(bp + j*16*LSTR);
#pragma unroll
    for(int i=0;i<4;i++){
      short8 afr = *(const short8*)(ap + i*16*LSTR);
#pragma unroll
      for(int j=0;j<8;j++)
        acc[i][j] = __builtin_amdgcn_mfma_f32_16x16x32_bf16(afr, bfr[j], acc[i][j], 0,0,0);
    }
    bar_lgkm();
  }

  ushort* cb = ct + (((size_t)(pp*4 + b)*256)<<12);
#pragma unroll
  for(int i=0;i<4;i++){
#pragma unroll
    for(int r=0;r<4;r++){
      int o = om0 + i*16 + hi*4 + r;
      ushort* row = cb + ((size_t)o<<12) + px0 + pn0 + lo;
#pragma unroll
      for(int j=0;j<8;j++) row[j*16] = f2bf(acc[i][j][r]);
    }
  }
}

// ---------- BN2 apply + relu + parity interleave: ct bf16 -> out f32 ----------
__global__ void k_bn2_apply(const ushort* __restrict__ ct, const float* __restrict__ stats,
                            const float* __restrict__ gamma, const float* __restrict__ beta,
                            float* __restrict__ out){
  int gid = blockIdx.x*256 + threadIdx.x;   // grid 16384
  int e4 = gid<<2;
  int b = e4>>22, o = (e4>>14)&255, q = e4&16383;
  int H2 = q>>7, W2 = q&127;
  int r = H2>>1, ph = H2&1, s0 = W2>>1;
  size_t base0 = (((size_t)((ph*2)*4 + b)*256 + o)<<12) + r*64 + s0;
  unsigned u0 = *(const unsigned*)(ct + base0);
  unsigned u1 = *(const unsigned*)(ct + base0 + ((size_t)4<<20));
  float m = stats[o*2], rstd = stats[o*2+1];
  float sc = rstd * gamma[o];
  float sh = beta[o] - m * sc;
  float4 v;
  v.x = fmaxf(bflo(u0)*sc + sh, 0.f);
  v.y = fmaxf(bflo(u1)*sc + sh, 0.f);
  v.z = fmaxf(bfhi(u0)*sc + sh, 0.f);
  v.w = fmaxf(bfhi(u1)*sc + sh, 0.f);
  *(float4*)(out + e4) = v;
}

extern "C" void kernel_launch(void* const* d_in, const int* in_sizes, int n_in,
                              void* d_out, int out_size, void* d_ws, size_t ws_size,
                              hipStream_t stream){
  (void)in_sizes; (void)n_in; (void)out_size; (void)ws_size;
  const float* x     = (const float*)d_in[0];
  const float* w_off = (const float*)d_in[1];
  const float* b_off = (const float*)d_in[2];
  const float* w_dcn = (const float*)d_in[3];
  const float* gamma1= (const float*)d_in[5];
  const float* beta1 = (const float*)d_in[6];
  const float* w_up  = (const float*)d_in[7];
  const float* gamma2= (const float*)d_in[8];
  const float* beta2 = (const float*)d_in[9];
  float* out = (float*)d_out;

  // Workspace (floats). ct (bf16, 32 MB = 8388608 floats) aliases om+xtb+out1,
  // all of which are dead before k_convt_mfma runs.
  float* ws   = (float*)d_ws;
  ushort* ct  = (ushort*)ws;                       // [0, 8388608) floats
  float* om   = ws;                                // 442368 floats
  ushort* xtb = (ushort*)(ws + 442368);            // 4194304 bf16 = 2097152 floats
  float* out1 = ws + 442368 + 2097152;             // 4194304 floats, ends 6733824 < 8388608
  float* base2 = ws + 8388608;
  ushort* y1b  = (ushort*)base2;                                   // 4194304 bf16
  ushort* WT2c = (ushort*)(base2 + 2097152);                       // 1048576 bf16
  ushort* Wdb  = (ushort*)(base2 + 2097152 + 524288);              // 589824 bf16
  ushort* Wob  = (ushort*)(base2 + 2097152 + 524288 + 294912);     // 73728 bf16
  float* st1   = base2 + 2097152 + 524288 + 294912 + 36864;        // 512
  float* st2   = st1 + 512;                                        // 512

  k_transpose_x <<<dim3(128,8,4), 256, 0, stream>>>(x, xtb);
  k_build_Wob   <<<288,  256, 0, stream>>>(w_off, Wob);
  k_build_Wdb   <<<2304, 256, 0, stream>>>(w_dcn, Wdb);
  k_build_WT2c  <<<4096, 256, 0, stream>>>(w_up, WT2c);
  k_offset_mfma <<<dim3(64,4),  256, 0, stream>>>(xtb, Wob, om);
  k_dcn_mfma    <<<dim3(64,4),  512, 0, stream>>>(xtb, om, b_off, Wdb, out1);
  k_bn_stats    <<<256,  256, 0, stream>>>(out1, st1, 4096);
  k_bn1_apply_t <<<dim3(128,8,4), 256, 0, stream>>>(out1, st1, gamma1, beta1, y1b);
  k_convt_mfma  <<<dim3(16,4,4),  512, 0, stream>>>(y1b, WT2c, ct);
  k_bn_stats_ct <<<256,  256, 0, stream>>>(ct, st2);
  k_bn2_apply   <<<16384,256, 0, stream>>>(ct, st2, gamma2, beta2, out);
}

// Round 4
// 289.129 us; speedup vs baseline: 1.1360x; 1.1360x over previous
//
#include <hip/hip_runtime.h>
#include <hip/hip_bf16.h>
#include <math.h>

// Problem constants
#define B_   4
#define CIN  256
#define COUT 256
#define HW   4096   // 64*64

typedef __attribute__((ext_vector_type(8))) short short8;
typedef __attribute__((ext_vector_type(4))) float float4v;

// LDS row strides (ushorts).
// LSTR  (32-ch rows):  80 B = 20 dwords -> 8-period bank pattern, 2-way (free).
// LSTR2 (64-ch rows): 144 B = 36 dwords -> 8-period bank pattern, 2-way (free).
#define LSTR  40
#define LSTR2 72

__device__ __forceinline__ float sigmoidf_(float v){ return 1.0f/(1.0f+expf(-v)); }
__device__ __forceinline__ ushort f2bf(float f){
  union { float f; unsigned u; } x; x.f = f;
  unsigned r = x.u + 0x7fffu + ((x.u>>16)&1u);
  return (ushort)(r>>16);
}
__device__ __forceinline__ float bflo(unsigned u){ union{unsigned u; float f;} c; c.u = u<<16;          return c.f; }
__device__ __forceinline__ float bfhi(unsigned u){ union{unsigned u; float f;} c; c.u = u & 0xffff0000u; return c.f; }

// ---------- transpose x [B][C][HW] -> xtb [B][HW][C] bf16 ----------
__global__ void k_transpose_x(const float* __restrict__ x, ushort* __restrict__ xtb){
  __shared__ float ts[32][33];
  int tx = threadIdx.x & 31, ty = threadIdx.x >> 5;
  int p0 = blockIdx.x * 32, c0 = blockIdx.y * 32, b = blockIdx.z;
  const float* xb = x + (size_t)b*CIN*HW;
#pragma unroll
  for(int q=0;q<4;q++){
    int c = ty + q*8;
    ts[c][tx] = xb[(size_t)(c0+c)*HW + p0+tx];
  }
  __syncthreads();
#pragma unroll
  for(int q=0;q<4;q++){
    int pr = ty + q*8;
    xtb[((size_t)(b*HW + p0+pr)<<8) + c0+tx] = f2bf(ts[tx][pr]);
  }
}

// ---------- weight re-layouts (bf16, K-chunked [kc][o][kk]) ----------
__global__ void k_build_Wob(const float* __restrict__ w_off, ushort* __restrict__ Wob){
  int f = blockIdx.x*256 + threadIdx.x;   // grid 288
  int kc = f>>10, o = (f>>5)&31, kk = f&31;
  int k = kc*32 + kk, tap = k>>8, c = k&255;
  float v = (o < 27) ? w_off[(size_t)o*2304 + c*9 + tap] : 0.f;
  Wob[f] = f2bf(v);
}
__global__ void k_build_Wdb(const float* __restrict__ w_dcn, ushort* __restrict__ Wdb){
  int f = blockIdx.x*256 + threadIdx.x;  // grid 2304
  int kc = f>>13, o = (f>>5)&255, kk = f&31;
  int k = kc>>3, c = ((kc&7)<<5) | kk;
  Wdb[f] = f2bf(w_dcn[(size_t)o*2304 + c*9 + k]);
}
__global__ void k_build_WT2c(const float* __restrict__ w_up, ushort* __restrict__ WT2c){
  int f = blockIdx.x*256 + threadIdx.x;    // grid 4096
  int pp = f>>18, kc = (f>>13)&31, o = (f>>5)&255, kk = f&31;
  int k = kc*32 + kk, ab = k>>8, c = k&255;
  int a = ab>>1, bb = ab&1, ph = pp>>1, pw = pp&1;
  WT2c[f] = f2bf(w_up[(size_t)(c*COUT+o)*16 + (3-ph-2*a)*4 + (3-pw-2*bb)]);
}

// ---------- offset conv MFMA: M=32(27), Nb=64 px, K=2304, PAIRED chunks (BK=64) ----------
// 36 pair-phases (was 72). Pair p = chunks {2p,2p+1}: same tap (2p even), 64 contiguous
// channels -> gather with uint4 (16B) loads, same instr count as one chunk before.
// grid (64,4), 256 thr = 4 waves. W direct global->reg.
__global__ __launch_bounds__(256) void k_offset_mfma(const ushort* __restrict__ xtb,
                        const ushort* __restrict__ Wob, float* __restrict__ om){
  __shared__ ushort Vs[2][64*LSTR2];
  __shared__ int sIdx[576];
  int tid = threadIdx.x;
  int px0 = blockIdx.x * 64;
  int b   = blockIdx.y;
  for(int t=tid; t<576; t+=256){
    int tap = t>>6, px = t&63;
    int p = px0+px, hh = p>>6, ww = p&63;
    int ih = hh + tap/3 - 1, iw = ww + tap%3 - 1;
    sIdx[t] = (ih>=0 && ih<64 && iw>=0 && iw<64) ? ((b*HW + ih*64+iw)<<8) : -1;
  }
  __syncthreads();

  int lane = tid&63, wv = tid>>6, lo = lane&15, hi = lane>>4;
  float4v acc[2];
  acc[0] = acc[1] = (float4v){0.f,0.f,0.f,0.f};
  int vpx = tid>>2, vseg = tid&3;
  const int wlane = lo*32 + hi*8;   // A-frag lane offset within a chunk

// pair gather: 16 ch/thread (2x uint4), 4 thr/px cover 64 ch
#define OFF_GATHER_P(PAIR, V0, V1) do{ \
    int k_ = (PAIR)>>2, c0_ = ((PAIR)&3)<<6; \
    int idx_ = sIdx[(k_<<6)+vpx]; \
    int coff_ = c0_ + (vseg<<4); \
    V0 = make_uint4(0,0,0,0); V1 = make_uint4(0,0,0,0); \
    if(idx_ >= 0){ \
      V0 = *(const uint4*)(xtb + idx_ + coff_); \
      V1 = *(const uint4*)(xtb + idx_ + coff_ + 8); \
    } \
  }while(0)

#define OFF_VWRITE_P(V0, V1, BUF) do{ \
    *(uint4*)(&Vs[BUF][vpx*LSTR2 + (vseg<<4)])     = V0; \
    *(uint4*)(&Vs[BUF][vpx*LSTR2 + (vseg<<4) + 8]) = V1; \
  }while(0)

#define OFF_WLOAD_P(PAIR, W) do{ \
    const ushort* wp_ = Wob + (((PAIR)*2)<<10) + wlane; \
    W[0] = *(const short8*)(wp_);        W[1] = *(const short8*)(wp_ + 512); \
    W[2] = *(const short8*)(wp_ + 1024); W[3] = *(const short8*)(wp_ + 1536); \
  }while(0)

#define OFF_COMPUTE_P(W, BUF) do{ \
    const ushort* bp_ = &Vs[BUF][(wv*16+lo)*LSTR2 + hi*8]; \
    short8 ba_ = *(const short8*)(bp_); \
    short8 bb_ = *(const short8*)(bp_ + 32); \
    acc[0] = __builtin_amdgcn_mfma_f32_16x16x32_bf16(W[0], ba_, acc[0], 0,0,0); \
    acc[1] = __builtin_amdgcn_mfma_f32_16x16x32_bf16(W[1], ba_, acc[1], 0,0,0); \
    acc[0] = __builtin_amdgcn_mfma_f32_16x16x32_bf16(W[2], bb_, acc[0], 0,0,0); \
    acc[1] = __builtin_amdgcn_mfma_f32_16x16x32_bf16(W[3], bb_, acc[1], 0,0,0); \
  }while(0)

  short8 wA[4], wB[4];
  uint4 vE0, vE1, vO0, vO1;
  // ---- prologue: W pair0 -> wA, V pair0 -> Vs[0], V pair1 -> regs ----
  OFF_WLOAD_P(0, wA);
  OFF_GATHER_P(0, vE0, vE1);
  OFF_VWRITE_P(vE0, vE1, 0);
  OFF_GATHER_P(1, vO0, vO1);
  __syncthreads();

#pragma unroll 1
  for(int pb=0; pb<36; pb+=2){
    { // even pair pb: compute Vs[0] with wA; gather pb+2->E; W pb+1->wB; write O->Vs[1]
      if(pb<34) OFF_GATHER_P(pb+2, vE0, vE1);
      OFF_WLOAD_P(pb+1, wB);
      OFF_COMPUTE_P(wA, 0);
      OFF_VWRITE_P(vO0, vO1, 1);
      __syncthreads();
    }
    { // odd pair pb+1: compute Vs[1] with wB; gather pb+3->O; W pb+2->wA; write E->Vs[0]
      if(pb<33) OFF_GATHER_P(pb+3, vO0, vO1);
      if(pb<34) OFF_WLOAD_P(pb+2, wA);
      OFF_COMPUTE_P(wB, 1);
      if(pb<34) OFF_VWRITE_P(vE0, vE1, 0);
      __syncthreads();
    }
  }
  int p = px0 + wv*16 + lo;
#pragma unroll
  for(int mi=0;mi<2;mi++){
    int ob = mi*16 + hi*4;
    float4v a = (mi==0) ? acc[0] : acc[1];
#pragma unroll
    for(int r=0;r<4;r++){
      int o = ob + r;
      if(o < 27) om[(size_t)(b*27+o)*HW + p] = a[r];
    }
  }
}

// ---------- DCN MFMA: Mb=256, Nb=64, K=2304, PAIRED chunks (BK=64) ----------
// 36 pair-phases (was 72). grid (64,4), 512 thr = 8 waves (2/SIMD).
// Wave wv: o-strip (wv>>1)*64, px-half (wv&1)*32 -> 16 MFMA/phase.
// Pair shares tap -> one sPk/sCf lookup, 4x uint4 corner gathers (8 ch each),
// one b128 blend-write per thread per phase. W direct global->reg.
// b_dcn dropped: BN1 subtracts the per-channel mean, so a uniform bias cancels.
#define DCN_GATHER_P(PAIR, C0,C1,C2,C3, CF) do{ \
    int k_ = (PAIR)>>2, c0_ = ((PAIR)&3)<<6; \
    int t_ = (k_<<6) + vpx; \
    int pk_ = sPk[t_]; CF = sCf[t_]; \
    int coff_ = c0_ + (vseg<<3); \
    int iy0_=pk_&63, iy1_=(pk_>>6)&63, ix0_=(pk_>>12)&63, ix1_=(pk_>>18)&63; \
    C0 = *(const uint4*)(xtb + cbase + (((iy0_<<6)+ix0_)<<8) + coff_); \
    C1 = *(const uint4*)(xtb + cbase + (((iy0_<<6)+ix1_)<<8) + coff_); \
    C2 = *(const uint4*)(xtb + cbase + (((iy1_<<6)+ix0_)<<8) + coff_); \
    C3 = *(const uint4*)(xtb + cbase + (((iy1_<<6)+ix1_)<<8) + coff_); \
  }while(0)

#define DCN_BLEND_P(C0,C1,C2,C3, CF, BUF) do{ \
    union{ ushort us[8]; uint4 q; } rr_; \
    rr_.us[0] = f2bf(CF.x*bflo(C0.x)+CF.y*bflo(C1.x)+CF.z*bflo(C2.x)+CF.w*bflo(C3.x)); \
    rr_.us[1] = f2bf(CF.x*bfhi(C0.x)+CF.y*bfhi(C1.x)+CF.z*bfhi(C2.x)+CF.w*bfhi(C3.x)); \
    rr_.us[2] = f2bf(CF.x*bflo(C0.y)+CF.y*bflo(C1.y)+CF.z*bflo(C2.y)+CF.w*bflo(C3.y)); \
    rr_.us[3] = f2bf(CF.x*bfhi(C0.y)+CF.y*bfhi(C1.y)+CF.z*bfhi(C2.y)+CF.w*bfhi(C3.y)); \
    rr_.us[4] = f2bf(CF.x*bflo(C0.z)+CF.y*bflo(C1.z)+CF.z*bflo(C2.z)+CF.w*bflo(C3.z)); \
    rr_.us[5] = f2bf(CF.x*bfhi(C0.z)+CF.y*bfhi(C1.z)+CF.z*bfhi(C2.z)+CF.w*bfhi(C3.z)); \
    rr_.us[6] = f2bf(CF.x*bflo(C0.w)+CF.y*bflo(C1.w)+CF.z*bflo(C2.w)+CF.w*bflo(C3.w)); \
    rr_.us[7] = f2bf(CF.x*bfhi(C0.w)+CF.y*bfhi(C1.w)+CF.z*bfhi(C2.w)+CF.w*bfhi(C3.w)); \
    *(uint4*)(&Vs[BUF][vpx*LSTR2 + (vseg<<3)]) = rr_.q; \
  }while(0)

#define DCN_WLOAD_P(PAIR, W) do{ \
    const ushort* wp_ = Wdb + ((size_t)((PAIR)*2)<<13) + wlane; \
    W[0] = *(const short8*)(wp_);         W[1] = *(const short8*)(wp_ + 512); \
    W[2] = *(const short8*)(wp_ + 1024);  W[3] = *(const short8*)(wp_ + 1536); \
    W[4] = *(const short8*)(wp_ + 8192);  W[5] = *(const short8*)(wp_ + 8704); \
    W[6] = *(const short8*)(wp_ + 9216);  W[7] = *(const short8*)(wp_ + 9728); \
  }while(0)

#define DCN_COMPUTE_P(W, BUF) do{ \
    const ushort* bp_ = &Vs[BUF][(pn0+lo)*LSTR2 + hi*8]; \
    short8 a0_ = *(const short8*)(bp_); \
    short8 a1_ = *(const short8*)(bp_ + 16*LSTR2); \
    short8 b0_ = *(const short8*)(bp_ + 32); \
    short8 b1_ = *(const short8*)(bp_ + 32 + 16*LSTR2); \
    _Pragma("unroll") \
    for(int i_=0;i_<4;i_++){ \
      acc[i_][0] = __builtin_amdgcn_mfma_f32_16x16x32_bf16(W[i_],   a0_, acc[i_][0], 0,0,0); \
      acc[i_][1] = __builtin_amdgcn_mfma_f32_16x16x32_bf16(W[i_],   a1_, acc[i_][1], 0,0,0); \
      acc[i_][0] = __builtin_amdgcn_mfma_f32_16x16x32_bf16(W[4+i_], b0_, acc[i_][0], 0,0,0); \
      acc[i_][1] = __builtin_amdgcn_mfma_f32_16x16x32_bf16(W[4+i_], b1_, acc[i_][1], 0,0,0); \
    } \
  }while(0)

__global__ __launch_bounds__(512) void k_dcn_mfma(const ushort* __restrict__ xtb,
                        const float* __restrict__ om, const float* __restrict__ b_off,
                        const ushort* __restrict__ Wdb, float* __restrict__ out1){
  __shared__ ushort Vs[2][64*LSTR2];   // 2 x 9216 B
  __shared__ int    sPk[576];
  __shared__ float4 sCf[576];
  int tid = threadIdx.x;
  int px0 = blockIdx.x * 64;
  int b   = blockIdx.y;

  for(int t=tid; t<576; t+=512){
    int k = t>>6, px = t&63;
    int p = px0 + px, hh = p>>6, ww = p&63;
    const float* omp = om + (size_t)b*27*HW + p;
    float dy = omp[(size_t)k*HW]      + b_off[k];
    float dx = omp[(size_t)(9+k)*HW]  + b_off[9+k];
    float mo = sigmoidf_(omp[(size_t)(18+k)*HW] + b_off[18+k]);
    float py  = dy + (float)(hh + k/3 - 1);
    float pxf = dx + (float)(ww + k%3 - 1);
    float y0 = floorf(py), x0 = floorf(pxf);
    float wy = py - y0, wx = pxf - x0;
    float y1 = y0 + 1.0f, x1 = x0 + 1.0f;
    bool vy0 = (y0>=0.f)&&(y0<=63.f), vy1 = (y1>=0.f)&&(y1<=63.f);
    bool vx0 = (x0>=0.f)&&(x0<=63.f), vx1 = (x1>=0.f)&&(x1<=63.f);
    int iy0 = (int)fminf(fmaxf(y0,0.f),63.f);
    int iy1 = (int)fminf(fmaxf(y1,0.f),63.f);
    int ix0 = (int)fminf(fmaxf(x0,0.f),63.f);
    int ix1 = (int)fminf(fmaxf(x1,0.f),63.f);
    sPk[t] = iy0 | (iy1<<6) | (ix0<<12) | (ix1<<18);
    sCf[t] = make_float4((vy0&&vx0)? (1.f-wy)*(1.f-wx)*mo : 0.f,
                         (vy0&&vx1)? (1.f-wy)*wx*mo       : 0.f,
                         (vy1&&vx0)? wy*(1.f-wx)*mo       : 0.f,
                         (vy1&&vx1)? wy*wx*mo             : 0.f);
  }
  __syncthreads();

  int lane = tid&63, wv = tid>>6, lo = lane&15, hi = lane>>4;
  int om0 = (wv>>1)*64, pn0 = (wv&1)*32;
  float4v acc[4][2];
#pragma unroll
  for(int i=0;i<4;i++)
#pragma unroll
    for(int j=0;j<2;j++) acc[i][j] = (float4v){0.f,0.f,0.f,0.f};
  int cbase = (b*HW)<<8;
  int vpx = tid>>3, vseg = tid&7;
  const int wlane = (om0+lo)*32 + hi*8;   // A-frag lane offset within a chunk

  short8 wA[8], wB[8];
  uint4 cE0,cE1,cE2,cE3, cO0,cO1,cO2,cO3;
  float4 fE, fO;

  // ---- prologue: W pair0 -> wA, gather+blend pair0 -> Vs[0], gather pair1 -> O ----
  DCN_WLOAD_P(0, wA);
  DCN_GATHER_P(0, cE0,cE1,cE2,cE3, fE);
  DCN_BLEND_P(cE0,cE1,cE2,cE3, fE, 0);
  DCN_GATHER_P(1, cO0,cO1,cO2,cO3, fO);
  __syncthreads();

#pragma unroll 1
  for(int pb=0; pb<36; pb+=2){
    { // even pair pb: compute Vs[0]/wA; gather pb+2->E; W pb+1->wB; blend O->Vs[1]
      if(pb<34) DCN_GATHER_P(pb+2, cE0,cE1,cE2,cE3, fE);
      DCN_WLOAD_P(pb+1, wB);
      DCN_COMPUTE_P(wA, 0);
      DCN_BLEND_P(cO0,cO1,cO2,cO3, fO, 1);
      __syncthreads();
    }
    { // odd pair pb+1: compute Vs[1]/wB; gather pb+3->O; W pb+2->wA; blend E->Vs[0]
      if(pb<33) DCN_GATHER_P(pb+3, cO0,cO1,cO2,cO3, fO);
      if(pb<34) DCN_WLOAD_P(pb+2, wA);
      DCN_COMPUTE_P(wB, 1);
      if(pb<34) DCN_BLEND_P(cE0,cE1,cE2,cE3, fE, 0);
      __syncthreads();
    }
  }

#pragma unroll
  for(int i=0;i<4;i++){
    int ob = om0 + i*16 + hi*4;
#pragma unroll
    for(int r=0;r<4;r++){
      int o = ob + r;
      float* op = out1 + (size_t)(b*COUT + o)*HW + px0 + pn0 + lo;
#pragma unroll
      for(int j=0;j<2;j++) op[j*16] = acc[i][j][r];
    }
  }
}

// ---------- batchnorm stats (f32 input, for out1) ----------
__global__ void k_bn_stats(const float* __restrict__ xin, float* __restrict__ stats, int per_b){
  int o = blockIdx.x, tid = threadIdx.x;
  float s=0.f, ss=0.f;
  for(int b=0;b<B_;b++){
    const float* p = xin + (size_t)(b*COUT+o)*per_b;
    for(int i=tid;i<per_b;i+=256){ float v = p[i]; s+=v; ss+=v*v; }
  }
  __shared__ float rs[256], rss[256];
  rs[tid]=s; rss[tid]=ss; __syncthreads();
  for(int st=128; st>0; st>>=1){
    if(tid<st){ rs[tid]+=rs[tid+st]; rss[tid]+=rss[tid+st]; }
    __syncthreads();
  }
  if(tid==0){
    float n = (float)(B_*per_b);
    float mean = rs[0]/n;
    float var  = rss[0]/n - mean*mean;
    stats[o*2] = mean; stats[o*2+1] = rsqrtf(var + 1e-5f);
  }
}

// ---------- batchnorm stats over bf16 ct [16 planes][o][4096] ----------
__global__ void k_bn_stats_ct(const ushort* __restrict__ ct, float* __restrict__ stats){
  int o = blockIdx.x, tid = threadIdx.x;
  float s=0.f, ss=0.f;
  for(int pl=0; pl<16; ++pl){
    const ushort* p = ct + (((size_t)(pl*256 + o))<<12);
    for(int i=tid*8; i<4096; i+=2048){
      uint4 v = *(const uint4*)(p + i);
      float f;
      f=bflo(v.x); s+=f; ss+=f*f;  f=bfhi(v.x); s+=f; ss+=f*f;
      f=bflo(v.y); s+=f; ss+=f*f;  f=bfhi(v.y); s+=f; ss+=f*f;
      f=bflo(v.z); s+=f; ss+=f*f;  f=bfhi(v.z); s+=f; ss+=f*f;
      f=bflo(v.w); s+=f; ss+=f*f;  f=bfhi(v.w); s+=f; ss+=f*f;
    }
  }
  __shared__ float rs[256], rss[256];
  rs[tid]=s; rss[tid]=ss; __syncthreads();
  for(int st=128; st>0; st>>=1){
    if(tid<st){ rs[tid]+=rs[tid+st]; rss[tid]+=rss[tid+st]; }
    __syncthreads();
  }
  if(tid==0){
    float n = (float)(16*4096);
    float mean = rs[0]/n;
    float var  = rss[0]/n - mean*mean;
    stats[o*2] = mean; stats[o*2+1] = rsqrtf(var + 1e-5f);
  }
}

// ---------- BN1 apply + relu + transpose -> y1b bf16 [b][p][c] ----------
__global__ void k_bn1_apply_t(const float* __restrict__ out1, const float* __restrict__ stats,
                              const float* __restrict__ gamma, const float* __restrict__ beta,
                              ushort* __restrict__ y1b){
  __shared__ float ts[32][33];
  int tx = threadIdx.x & 31, ty = threadIdx.x >> 5;
  int p0 = blockIdx.x*32, o0 = blockIdx.y*32, b = blockIdx.z;
#pragma unroll
  for(int q=0;q<4;q++){
    int oo = ty + q*8; int o = o0 + oo;
    float m = stats[o*2], rstd = stats[o*2+1];
    float scale = rstd * gamma[o];
    float shift = beta[o] - m * scale;
    float v = out1[(size_t)(b*COUT+o)*HW + p0+tx];
    ts[oo][tx] = fmaxf(v*scale + shift, 0.f);
  }
  __syncthreads();
#pragma unroll
  for(int q=0;q<4;q++){
    int pr = ty + q*8;
    y1b[((size_t)(b*HW + p0+pr)<<8) + o0+tx] = f2bf(ts[tx][pr]);
  }
}

// ---------- conv-transpose MFMA: Mb=256 o, Nb=256 px, one (b,pp) ----------
// Double-buffered Ws/Vs, 1 barrier per chunk (was 2): 32 sync points.
__global__ __launch_bounds__(512) void k_convt_mfma(const ushort* __restrict__ y1b,
                        const ushort* __restrict__ WT2c,
                        ushort* __restrict__ ct){
  __shared__ ushort Ws[2][256*LSTR];
  __shared__ ushort Vs[2][256*LSTR];
  __shared__ int sIdx[1024];
  int tid = threadIdx.x;
  int px0 = blockIdx.x * 256;
  int b   = blockIdx.y;
  int pp  = blockIdx.z;
  int ph = pp>>1, pw = pp&1;

  for(int t=tid; t<1024; t+=512){
    int ab = t>>8, px = t&255;
    int a = ab>>1, bb = ab&1;
    int p = px0+px, r = p>>6, s = p&63;
    int ih = r + ph - 1 + a, iw = s + pw - 1 + bb;
    sIdx[t] = (ih>=0 && ih<64 && iw>=0 && iw<64) ? ((b*HW + ih*64+iw)<<8) : -1;
  }
  __syncthreads();

  int lane = tid&63, wv = tid>>6, lo = lane&15, hi = lane>>4;
  int om0 = (wv>>1)*64;
  int pn0 = (wv&1)*128;
  float4v acc[4][8];
#pragma unroll
  for(int i=0;i<4;i++)
#pragma unroll
    for(int j=0;j<8;j++) acc[i][j] = (float4v){0.f,0.f,0.f,0.f};

  const ushort* wbase = WT2c + ((size_t)pp<<18);
  uint4 wpre[2], vpre[2];
  int g1 = tid + 512;
  int vpx = tid>>1, co = (tid&1)*16;

#define CT_PREFETCH(KN) do{ \
    const ushort* wp_ = wbase + ((KN)<<13); \
    wpre[0] = *(const uint4*)(wp_ + tid*8); \
    wpre[1] = *(const uint4*)(wp_ + g1*8); \
    int ab_ = (KN)>>3, c0_ = ((KN)&7)<<5; \
    int idx_ = sIdx[(ab_<<8) + vpx]; \
    int co_ = c0_ + co; \
    vpre[0] = make_uint4(0,0,0,0); vpre[1] = make_uint4(0,0,0,0); \
    if(idx_ >= 0){ \
      vpre[0] = *(const uint4*)(y1b + idx_ + co_); \
      vpre[1] = *(const uint4*)(y1b + idx_ + co_ + 8); \
    } \
  }while(0)

#define CT_WRITE(BUF) do{ \
    *(uint4*)(&Ws[BUF][(tid>>2)*LSTR + (tid&3)*8]) = wpre[0]; \
    *(uint4*)(&Ws[BUF][(g1>>2)*LSTR + (g1&3)*8])   = wpre[1]; \
    *(uint4*)(&Vs[BUF][vpx*LSTR + co])     = vpre[0]; \
    *(uint4*)(&Vs[BUF][vpx*LSTR + co + 8]) = vpre[1]; \
  }while(0)

  // ---- prologue: chunk0 -> buf0 ----
  CT_PREFETCH(0);
  CT_WRITE(0);
  __syncthreads();

#pragma unroll 1
  for(int kc=0; kc<32; ++kc){
    int cur = kc&1;
    if(kc < 31) CT_PREFETCH(kc+1);
    const ushort* ap = &Ws[cur][(om0 + lo)*LSTR + hi*8];
    const ushort* bp = &Vs[cur][(pn0 + lo)*LSTR + hi*8];
    short8 bfr[8];
#pragma unroll
    for(int j=0;j<8;j++) bfr[j] = *(const short8*)(bp + j*16*LSTR);
#pragma unroll
    for(int i=0;i<4;i++){
      short8 afr = *(const short8*)(ap + i*16*LSTR);
#pragma unroll
      for(int j=0;j<8;j++)
        acc[i][j] = __builtin_amdgcn_mfma_f32_16x16x32_bf16(afr, bfr[j], acc[i][j], 0,0,0);
    }
    if(kc < 31) CT_WRITE(cur^1);
    __syncthreads();
  }

  ushort* cb = ct + (((size_t)(pp*4 + b)*256)<<12);
#pragma unroll
  for(int i=0;i<4;i++){
#pragma unroll
    for(int r=0;r<4;r++){
      int o = om0 + i*16 + hi*4 + r;
      ushort* row = cb + ((size_t)o<<12) + px0 + pn0 + lo;
#pragma unroll
      for(int j=0;j<8;j++) row[j*16] = f2bf(acc[i][j][r]);
    }
  }
}

// ---------- BN2 apply + relu + parity interleave: ct bf16 -> out f32 ----------
__global__ void k_bn2_apply(const ushort* __restrict__ ct, const float* __restrict__ stats,
                            const float* __restrict__ gamma, const float* __restrict__ beta,
                            float* __restrict__ out){
  int gid = blockIdx.x*256 + threadIdx.x;   // grid 16384
  int e4 = gid<<2;
  int b = e4>>22, o = (e4>>14)&255, q = e4&16383;
  int H2 = q>>7, W2 = q&127;
  int r = H2>>1, ph = H2&1, s0 = W2>>1;
  size_t base0 = (((size_t)((ph*2)*4 + b)*256 + o)<<12) + r*64 + s0;
  unsigned u0 = *(const unsigned*)(ct + base0);
  unsigned u1 = *(const unsigned*)(ct + base0 + ((size_t)4<<20));
  float m = stats[o*2], rstd = stats[o*2+1];
  float sc = rstd * gamma[o];
  float sh = beta[o] - m * sc;
  float4 v;
  v.x = fmaxf(bflo(u0)*sc + sh, 0.f);
  v.y = fmaxf(bflo(u1)*sc + sh, 0.f);
  v.z = fmaxf(bfhi(u0)*sc + sh, 0.f);
  v.w = fmaxf(bfhi(u1)*sc + sh, 0.f);
  *(float4*)(out + e4) = v;
}

extern "C" void kernel_launch(void* const* d_in, const int* in_sizes, int n_in,
                              void* d_out, int out_size, void* d_ws, size_t ws_size,
                              hipStream_t stream){
  (void)in_sizes; (void)n_in; (void)out_size; (void)ws_size;
  const float* x     = (const float*)d_in[0];
  const float* w_off = (const float*)d_in[1];
  const float* b_off = (const float*)d_in[2];
  const float* w_dcn = (const float*)d_in[3];
  const float* gamma1= (const float*)d_in[5];
  const float* beta1 = (const float*)d_in[6];
  const float* w_up  = (const float*)d_in[7];
  const float* gamma2= (const float*)d_in[8];
  const float* beta2 = (const float*)d_in[9];
  float* out = (float*)d_out;

  // Workspace (floats). ct (bf16, 32 MB = 8388608 floats) aliases om+xtb+out1,
  // all of which are dead before k_convt_mfma runs.
  float* ws   = (float*)d_ws;
  ushort* ct  = (ushort*)ws;                       // [0, 8388608) floats
  float* om   = ws;                                // 442368 floats
  ushort* xtb = (ushort*)(ws + 442368);            // 4194304 bf16 = 2097152 floats
  float* out1 = ws + 442368 + 2097152;             // 4194304 floats, ends 6733824 < 8388608
  float* base2 = ws + 8388608;
  ushort* y1b  = (ushort*)base2;                                   // 4194304 bf16
  ushort* WT2c = (ushort*)(base2 + 2097152);                       // 1048576 bf16
  ushort* Wdb  = (ushort*)(base2 + 2097152 + 524288);              // 589824 bf16
  ushort* Wob  = (ushort*)(base2 + 2097152 + 524288 + 294912);     // 73728 bf16
  float* st1   = base2 + 2097152 + 524288 + 294912 + 36864;        // 512
  float* st2   = st1 + 512;                                        // 512

  k_transpose_x <<<dim3(128,8,4), 256, 0, stream>>>(x, xtb);
  k_build_Wob   <<<288,  256, 0, stream>>>(w_off, Wob);
  k_build_Wdb   <<<2304, 256, 0, stream>>>(w_dcn, Wdb);
  k_build_WT2c  <<<4096, 256, 0, stream>>>(w_up, WT2c);
  k_offset_mfma <<<dim3(64,4),  256, 0, stream>>>(xtb, Wob, om);
  k_dcn_mfma    <<<dim3(64,4),  512, 0, stream>>>(xtb, om, b_off, Wdb, out1);
  k_bn_stats    <<<256,  256, 0, stream>>>(out1, st1, 4096);
  k_bn1_apply_t <<<dim3(128,8,4), 256, 0, stream>>>(out1, st1, gamma1, beta1, y1b);
  k_convt_mfma  <<<dim3(16,4,4),  512, 0, stream>>>(y1b, WT2c, ct);
  k_bn_stats_ct <<<256,  256, 0, stream>>>(ct, st2);
  k_bn2_apply   <<<16384,256, 0, stream>>>(ct, st2, gamma2, beta2, out);
}